// Round 17
// baseline (278.605 us; speedup 1.0000x reference)
//
#include <hip/hip_runtime.h>

#define BATCH 131072

typedef __attribute__((ext_vector_type(8))) __bf16 bf16x8;
typedef __attribute__((ext_vector_type(16))) float f32x16;
typedef __attribute__((ext_vector_type(2))) float f32x2;

__constant__ int FOFF[23] = {0,4,8,12,16,20,24,28,32,36,40,44,48,50,52,53,57,58,59,60,61,62,63};
__constant__ int FDIM[23] = {4,4,4,4,4,4,4,4,4,4,4,4,2,2,1,4,1,1,1,1,1,1,2};

__device__ __forceinline__ unsigned short f2bf(float f){
  unsigned int u = __float_as_uint(f);
  u += 0x7fffu + ((u>>16)&1u);   // RNE
  return (unsigned short)(u>>16);
}
__device__ __forceinline__ unsigned int packpair(float a, float b){
  return (unsigned int)f2bf(a) | ((unsigned int)f2bf(b)<<16);
}
__device__ __forceinline__ float bflo(unsigned int u){ return __uint_as_float(u<<16); }
__device__ __forceinline__ float bfhi(unsigned int u){ return __uint_as_float(u & 0xffff0000u); }

// ---------------- prep: pack W1..W5 into MFMA-B fragment-linear bf16 layout ----------------
__global__ void prep_weights(const float* __restrict__ W1, const float* __restrict__ W2,
    const float* __restrict__ W3, const float* __restrict__ W4, const float* __restrict__ W5,
    unsigned short* __restrict__ wpack){
  int idx = blockIdx.x*256 + threadIdx.x;
  if (idx >= 22656) return;
  const float* W; int rel; int Kd;
  if (idx < 5760){ W = W1; rel = idx; Kd = 230; }
  else {
    int r2 = idx - 5760;
    int li = r2 / 4224; rel = r2 - li*4224; Kd = 164;
    W = (li==0)?W2:((li==1)?W3:((li==2)?W4:W5));
  }
  int lane = rel & 63, rem = rel >> 6;
  int nt = rem % 6, ks = rem / 6;
  int n  = nt*32 + (lane&31);
  int k0 = ks*16 + ((lane>>5)<<3);
  unsigned int v[4];
  #pragma unroll
  for (int p=0;p<4;p++){
    int ka = k0 + 2*p, kb = ka+1;
    float fa = (ka<Kd && n<164) ? W[ka*164+n] : 0.f;
    float fb = (kb<Kd && n<164) ? W[kb*164+n] : 0.f;
    v[p] = packpair(fa, fb);
  }
  *(uint4*)(wpack + (size_t)idx*8) = make_uint4(v[0],v[1],v[2],v[3]);
}

// ---------------- prep: small-weights image ----------------
// word layout: [0,1380) proj PAIR-packed (12 words per output-pair, [10]=roff);
// [1380,1500) M=WqWk^T/sqrt(10) [10][12] f32; [1500,1620) Wv [10][12] f32;
// [1620,2604) head weights f32 [6][164] (k-major).
__global__ void prep_small(const float* __restrict__ Wproj, const float* __restrict__ bproj,
    const float* __restrict__ Wq, const float* __restrict__ Wk, const float* __restrict__ Wv,
    const float* __restrict__ Wmove, const float* __restrict__ Wmark,
    unsigned int* __restrict__ swimg){
  int idx = blockIdx.x*256 + threadIdx.x;
  if (idx >= 2604) return;
  unsigned int outv;
  if (idx < 1380){
    int p = idx/12, rem = idx - p*12;
    int fi = p/5;                    // 5 output-pairs per feature
    int roff = FOFF[fi], dims = FDIM[fi];
    if (rem < 8){
      int u = rem>>1, odd = rem&1;
      float v = (u < dims) ? Wproj[(roff+u)*230 + 2*p+odd] : 0.f;
      outv = __float_as_uint(v);
    } else if (rem < 10){
      outv = __float_as_uint(bproj[2*p + (rem-8)]);
    } else if (rem == 10){
      outv = (unsigned int)roff;
    } else outv = 0u;
  } else if (idx < 1500){
    int r = idx-1380, e = r/12, d = r-12*e;
    float v = 0.f;
    if (d<10){ float ssum=0.f;
      #pragma unroll
      for (int k2=0;k2<10;k2++) ssum += Wq[e*10+k2]*Wk[d*10+k2];
      v = ssum*0.31622776601683794f; }
    outv = __float_as_uint(v);
  } else if (idx < 1620){
    int r = idx-1500, e = r/12, d = r-12*e;
    outv = __float_as_uint((d<10)? Wv[e*10+d] : 0.f);
  } else {
    int r = idx-1620;            // 0..983
    int o = r/164, k = r-o*164;  // k 0..163
    outv = __float_as_uint((o<5)? Wmove[k*5+o] : Wmark[k]);
  }
  swimg[idx] = outv;
}

// ================= SPLIT PATH (used when ws_size is large enough) =================

// ---------------- attention: ONE query row of one sample, h f32 pairs (pitch 16) -------------
__device__ __forceinline__ void attn1g(int s, int i, int S0,
    const f32x2* hf2, const f32x2* swf2, unsigned int* __restrict__ zg){
  f32x2 g2[5];
  #pragma unroll
  for (int p=0;p<5;p++) g2[p] = (f32x2){0.f,0.f};
  {
    f32x2 hi2[5];
    #pragma unroll
    for (int p=0;p<5;p++) hi2[p] = hf2[(i*5+p)*16 + s];
    #pragma unroll
    for (int e=0;e<10;e++){
      float he = (e&1) ? hi2[e>>1].y : hi2[e>>1].x;
      #pragma unroll
      for (int p=0;p<5;p++) g2[p] += swf2[e*6 + p]*he;
    }
  }
  f32x2 st2[5]; float tau = 0.f;
  #pragma unroll
  for (int p=0;p<5;p++) st2[p] = (f32x2){0.f,0.f};
  for (int j=0;j<23;j++){
    f32x2 hj[5];
    #pragma unroll
    for (int p=0;p<5;p++) hj[p] = hf2[(j*5+p)*16 + s];
    f32x2 l2 = (g2[0]*hj[0] + g2[1]*hj[1]) + (g2[2]*hj[2] + g2[3]*hj[3]) + g2[4]*hj[4];
    float e = __expf(l2.x + l2.y);
    tau += e;
    #pragma unroll
    for (int p=0;p<5;p++) st2[p] += hj[p]*e;
  }
  {
    float inv = 1.f/tau;
    #pragma unroll
    for (int p=0;p<5;p++) st2[p] *= inv;
  }
  f32x2 ct2[5];
  #pragma unroll
  for (int p=0;p<5;p++) ct2[p] = (f32x2){0.f,0.f};
  #pragma unroll
  for (int e=0;e<10;e++){
    float se = (e&1) ? st2[e>>1].y : st2[e>>1].x;
    #pragma unroll
    for (int p=0;p<5;p++) ct2[p] += swf2[60 + e*6 + p]*se;
  }
  #pragma unroll
  for (int p=0;p<5;p++){
    f32x2 h = hf2[(i*5+p)*16 + s];
    float z0 = h.x + ct2[p].x;
    float z1 = h.y + ct2[p].y;
    unsigned int r;
    asm volatile("v_cvt_pk_bf16_f32 %0, %1, %2" : "=v"(r) : "v"(z0), "v"(z1));
    zg[(size_t)(i*5+p)*BATCH + S0 + s] = r;
  }
}

// ---------------- KERNEL A: attention only. 16 samples / 512 thr / 4 blocks/CU ----------------
__global__ __launch_bounds__(512, 4) void attn_kernel(
    const float* __restrict__ xg, const unsigned short* __restrict__ wpack,
    unsigned int* __restrict__ zg)
{
  __shared__ __align__(16) unsigned char LDS[25424];
  float* xb = (float*)LDS;
  const f32x2* pw2 = (const f32x2*)(LDS + 4224);
  const unsigned int* pwu = (const unsigned int*)(LDS + 4224);
  const f32x2* swf2 = (const f32x2*)(LDS + 9744);
  unsigned int* sww = (unsigned int*)(LDS + 9744);
  f32x2* hf2 = (f32x2*)(LDS + 10704);

  const int t = threadIdx.x;
  const int S0 = blockIdx.x*16;

  {
    const float4* src4 = (const float4*)(xg + (size_t)S0*65);
    float4* x4 = (float4*)LDS;
    if (t < 260) x4[t] = src4[t];    // 16*65 = 1040 floats
    if (t < 8) xb[1040+t] = 0.f;
    const unsigned int* swsrc = (const unsigned int*)(wpack + 181248);
    for (int idx=t; idx<1380; idx+=512) ((unsigned int*)(LDS+4224))[idx] = swsrc[idx];
    if (t < 240) sww[t] = swsrc[1380+t];   // M + Wv
  }
  __syncthreads();

  for (int L=t; L<1840; L+=512){
    int s = L & 15, k = L>>4;
    int roff = (int)pwu[k*12 + 10];
    f32x2 acc = pw2[k*6 + 4];
    #pragma unroll
    for (int u=0;u<4;u++){
      float xv = xb[s*65 + roff + u];
      acc += pw2[k*6 + u] * xv;
    }
    hf2[k*16 + s] = acc;
  }
  __syncthreads();

  {
    const int s = t & 15;
    const int row = t >> 4;
    if (row < 23) attn1g(s, row, S0, hf2, swf2, zg);
  }
}

// ---------------- MFMA MLP inner: NT n-tiles for one 32-row M-tile (R5-proven) ----------------
template<int KSTEPS, int NT>
__device__ __forceinline__ void mlp_tiles(const unsigned short* abase, const bf16x8* wb,
    const float* __restrict__ bias, unsigned short* out16, int nt0, int colb, int rowb){
  f32x16 acc[NT];
  #pragma unroll
  for (int nt=0; nt<NT; ++nt)
    #pragma unroll
    for (int r=0;r<16;r++) acc[nt][r]=0.f;
  #pragma unroll
  for (int ks=0; ks<KSTEPS; ++ks){
    bf16x8 a = *(const bf16x8*)(abase + ks*16);
    const bf16x8* wk = wb + ks*(6*64);
    #pragma unroll
    for (int nt=0; nt<NT; ++nt)
      acc[nt] = __builtin_amdgcn_mfma_f32_32x32x16_bf16(a, wk[nt*64], acc[nt], 0,0,0);
  }
  #pragma unroll
  for (int nt=0; nt<NT; ++nt){
    int n = (nt0+nt)*32 + colb;
    float b = (n<164) ? bias[n] : 0.f;
    #pragma unroll
    for (int r=0;r<16;r++){
      int row = rowb + (r&3) + 8*(r>>2);
      float v = fmaxf(acc[nt][r] + b, 0.f);
      out16[row*200 + n] = f2bf(v);
    }
  }
}

// 64 rows, 8 waves: 2 M-tiles x N-groups {2,2,1,1} of the 6 N-tiles (R5-proven geometry)
template<int KSTEPS>
__device__ __forceinline__ void mlp_layer8(const unsigned short* in16, int inPitch,
    const bf16x8* __restrict__ wp, const float* __restrict__ bias,
    unsigned short* out16, int t){
  const int lane = t & 63;
  const int w = t >> 6;      // 0..7
  const int mt = w & 1;
  const int ng = w >> 1;
  const unsigned short* abase = in16 + (mt*32 + (lane&31))*inPitch + ((lane>>5)<<3);
  const int colb = lane&31;
  const int rowb = mt*32 + 4*(lane>>5);
  if (ng < 2){
    const int nt0 = 2*ng;
    mlp_tiles<KSTEPS,2>(abase, wp + nt0*64 + lane, bias, out16, nt0, colb, rowb);
  } else {
    const int nt0 = ng + 2;
    mlp_tiles<KSTEPS,1>(abase, wp + nt0*64 + lane, bias, out16, nt0, colb, rowb);
  }
}

// ---------------- KERNEL B: MLP+heads. 64 samples / 512 thr / 2 blocks/CU --------------------
__global__ __launch_bounds__(512, 2) void mlp_kernel(
    const unsigned int* __restrict__ zg,
    const float* __restrict__ b1, const float* __restrict__ b2, const float* __restrict__ b3,
    const float* __restrict__ b4, const float* __restrict__ b5,
    const float* __restrict__ bmove, const float* __restrict__ bmark,
    const unsigned short* __restrict__ wpack, float* __restrict__ out)
{
  __shared__ __align__(16) unsigned char LDS[61280];
  unsigned int* z32 = (unsigned int*)LDS;
  unsigned short* z16 = (unsigned short*)LDS;
  unsigned short* a16 = (unsigned short*)(LDS + 31744);
  const f32x2* hwf2 = (const f32x2*)(LDS + 57344);
  unsigned int* hww = (unsigned int*)(LDS + 57344);

  const int t = threadIdx.x;
  const int S0 = blockIdx.x*64;

  for (int idx=t; idx<7360; idx+=512){
    int s = idx & 63, k = idx >> 6;          // k 0..114
    z32[s*124 + k] = zg[(size_t)k*BATCH + S0 + s];
  }
  for (int idx=t; idx<320; idx+=512){
    int s = idx & 63, k = 115 + (idx >> 6);  // pad cols 115..119
    z32[s*124 + k] = 0u;
  }
  {
    const unsigned int* swsrc = (const unsigned int*)(wpack + 181248);
    for (int idx=t; idx<984; idx+=512) hww[idx] = swsrc[1620+idx];
  }
  __syncthreads();

  const bf16x8* wpk = (const bf16x8*)wpack;
  mlp_layer8<15>(z16, 248, wpk,          b1, a16, t); __syncthreads();
  mlp_layer8<11>(a16, 200, wpk + 5760,   b2, z16, t); __syncthreads();
  mlp_layer8<11>(z16, 200, wpk + 9984,   b3, a16, t); __syncthreads();
  mlp_layer8<11>(a16, 200, wpk + 14208,  b4, z16, t); __syncthreads();
  mlp_layer8<11>(z16, 200, wpk + 18432,  b5, a16, t); __syncthreads();

  if (t < 384){
    int s2 = t & 63, o = t >> 6;
    const unsigned int* ar = (const unsigned int*)(a16 + s2*200);
    const f32x2* hw = hwf2 + o*82;
    f32x2 acc2 = {0.f,0.f};
    for (int kp=0; kp<82; ++kp){
      unsigned int ua = ar[kp];
      f32x2 av; av.x = bflo(ua); av.y = bfhi(ua);
      acc2 += av * hw[kp];
    }
    float acc = acc2.x + acc2.y + ((o<5)? bmove[o] : bmark[0]);
    if (o<5) out[(size_t)(S0+s2)*5 + o] = acc;
    else     out[(size_t)BATCH*5 + S0 + s2] = acc;
  }
}

// ================= FUSED FALLBACK (R15, measured 177 us/dispatch, passes) =================

__device__ __forceinline__ void attn1(int s, int i,
    const f32x2* hf2, const f32x2* swf2, unsigned int* z32){
  f32x2 g2[5];
  #pragma unroll
  for (int p=0;p<5;p++) g2[p] = (f32x2){0.f,0.f};
  {
    f32x2 hi2[5];
    #pragma unroll
    for (int p=0;p<5;p++) hi2[p] = hf2[(i*5+p)*32 + s];
    #pragma unroll
    for (int e=0;e<10;e++){
      float he = (e&1) ? hi2[e>>1].y : hi2[e>>1].x;
      #pragma unroll
      for (int p=0;p<5;p++) g2[p] += swf2[e*6 + p]*he;
    }
  }
  f32x2 st2[5]; float tau = 0.f;
  #pragma unroll
  for (int p=0;p<5;p++) st2[p] = (f32x2){0.f,0.f};
  for (int j=0;j<23;j++){
    f32x2 hj[5];
    #pragma unroll
    for (int p=0;p<5;p++) hj[p] = hf2[(j*5+p)*32 + s];
    f32x2 l2 = (g2[0]*hj[0] + g2[1]*hj[1]) + (g2[2]*hj[2] + g2[3]*hj[3]) + g2[4]*hj[4];
    float e = __expf(l2.x + l2.y);
    tau += e;
    #pragma unroll
    for (int p=0;p<5;p++) st2[p] += hj[p]*e;
  }
  {
    float inv = 1.f/tau;
    #pragma unroll
    for (int p=0;p<5;p++) st2[p] *= inv;
  }
  f32x2 ct2[5];
  #pragma unroll
  for (int p=0;p<5;p++) ct2[p] = (f32x2){0.f,0.f};
  #pragma unroll
  for (int e=0;e<10;e++){
    float se = (e&1) ? st2[e>>1].y : st2[e>>1].x;
    #pragma unroll
    for (int p=0;p<5;p++) ct2[p] += swf2[60 + e*6 + p]*se;
  }
  #pragma unroll
  for (int p=0;p<5;p++){
    f32x2 h = hf2[(i*5+p)*32 + s];
    float z0 = h.x + ct2[p].x;
    float z1 = h.y + ct2[p].y;
    unsigned int r;
    asm volatile("v_cvt_pk_bf16_f32 %0, %1, %2" : "=v"(r) : "v"(z0), "v"(z1));
    z32[s*124 + i*5 + p] = r;
  }
}

template<int KSTEPS>
__device__ __forceinline__ void mlp_layer12(const unsigned short* in16, int inPitch,
    const bf16x8* __restrict__ wp, const float* __restrict__ bias,
    unsigned short* out16, int t){
  const int lane = t & 63;
  const int nt = t >> 6;     // 0..11; only 0..5 carry tiles
  if (nt >= 6) return;
  const unsigned short* abase = in16 + (lane&31)*inPitch + ((lane>>5)<<3);
  const bf16x8* wb = wp + nt*64 + lane;
  f32x16 acc;
  #pragma unroll
  for (int r=0;r<16;r++) acc[r]=0.f;
  #pragma unroll
  for (int ks=0; ks<KSTEPS; ++ks){
    bf16x8 a = *(const bf16x8*)(abase + ks*16);
    acc = __builtin_amdgcn_mfma_f32_32x32x16_bf16(a, wb[ks*(6*64)], acc, 0,0,0);
  }
  const int colb = lane&31;
  const int rowb = 4*(lane>>5);
  int n = nt*32 + colb;
  float b = (n<164) ? bias[n] : 0.f;
  #pragma unroll
  for (int r=0;r<16;r++){
    int row = rowb + (r&3) + 8*(r>>2);
    float v = fmaxf(acc[r] + b, 0.f);
    out16[row*200 + n] = f2bf(v);
  }
}

__global__ __launch_bounds__(768, 2) void actor_main(
    const float* __restrict__ xg,
    const float* __restrict__ b1, const float* __restrict__ b2, const float* __restrict__ b3,
    const float* __restrict__ b4, const float* __restrict__ b5,
    const float* __restrict__ bmove, const float* __restrict__ bmark,
    const unsigned short* __restrict__ wpack, float* __restrict__ out)
{
  __shared__ __align__(16) unsigned char LDS[50208];
  float* xb = (float*)LDS;
  unsigned int* xw = (unsigned int*)LDS;
  unsigned int* z32 = (unsigned int*)LDS;
  unsigned short* z16 = (unsigned short*)LDS;
  f32x2* hf2 = (f32x2*)(LDS + 15872);
  unsigned short* a16 = (unsigned short*)(LDS + 15872);
  const f32x2* swf2 = (const f32x2*)(LDS + 45312);
  unsigned int* swpw = (unsigned int*)(LDS + 45312);

  const int t = threadIdx.x;
  const int S0 = blockIdx.x*32;

  {
    const float4* src4 = (const float4*)(xg + (size_t)S0*65);
    float4* x4 = (float4*)LDS;
    if (t < 520) x4[t] = src4[t];
    if (t<8) xb[2080+t] = 0.f;
    const unsigned int* swsrc = (const unsigned int*)(wpack + 181248);
    for (int idx=t; idx<1380; idx+=768) xw[2088+idx] = swsrc[idx];
    for (int idx=t; idx<1224; idx+=768) swpw[idx] = swsrc[1380+idx];
  }
  __syncthreads();

  {
    const f32x2* pw2 = (const f32x2*)(xb + 2088);
    const unsigned int* pwu = (const unsigned int*)(xb + 2088);
    for (int L=t; L<3680; L+=768){
      int s = L & 31, k = L>>5;
      int roff = (int)pwu[k*12 + 10];
      f32x2 acc = pw2[k*6 + 4];
      #pragma unroll
      for (int u=0;u<4;u++){
        float xv = xb[s*65 + roff + u];
        acc += pw2[k*6 + u] * xv;
      }
      hf2[k*32 + s] = acc;
    }
  }
  __syncthreads();

  {
    const int s = t & 31;
    const int row = t >> 5;
    if (row < 23){
      attn1(s, row, hf2, swf2, z32);
    } else {
      for (int idx = s; idx < 160; idx += 32){
        int ss = idx/5, pc = idx-5*ss;
        z32[ss*124 + 115+pc] = 0u;
      }
    }
  }
  __syncthreads();

  const bf16x8* wpk = (const bf16x8*)wpack;
  mlp_layer12<15>(z16, 248, wpk,          b1, a16, t); __syncthreads();
  mlp_layer12<11>(a16, 200, wpk + 5760,   b2, z16, t); __syncthreads();
  mlp_layer12<11>(z16, 200, wpk + 9984,   b3, a16, t); __syncthreads();
  mlp_layer12<11>(a16, 200, wpk + 14208,  b4, z16, t); __syncthreads();
  mlp_layer12<11>(z16, 200, wpk + 18432,  b5, a16, t); __syncthreads();

  {
    float* pb = (float*)LDS;
    {
      int s2 = t & 31, r = t>>5;
      int o = r>>2, quarter = r&3;
      const uint4* ar4 = (const uint4*)(a16 + s2*200);
      const f32x2* hw = swf2 + 120 + o*82;
      f32x2 acc2 = {0.f,0.f};
      int q0 = quarter*5, q1 = q0+5;
      for (int q4=q0; q4<q1; ++q4){
        uint4 v = ar4[q4];
        unsigned int wv[4] = {v.x,v.y,v.z,v.w};
        #pragma unroll
        for (int e=0;e<4;e++){
          f32x2 av; av.x = bflo(wv[e]); av.y = bfhi(wv[e]);
          acc2 += av * hw[q4*4+e];
        }
      }
      if (quarter==3){
        const unsigned int* ar = (const unsigned int*)(a16 + s2*200);
        #pragma unroll
        for (int kp=80;kp<82;kp++){
          unsigned int u = ar[kp];
          f32x2 av; av.x = bflo(u); av.y = bfhi(u);
          acc2 += av * hw[kp];
        }
      }
      pb[r*32 + s2] = acc2.x + acc2.y;
    }
    __syncthreads();
    if (t < 192){
      int s2 = t & 31, o = t>>5;
      float acc = pb[(4*o)*32 + s2] + pb[(4*o+1)*32 + s2]
                + pb[(4*o+2)*32 + s2] + pb[(4*o+3)*32 + s2];
      acc += (o<5)? bmove[o] : bmark[0];
      if (o<5) out[(size_t)(S0+s2)*5 + o] = acc;
      else     out[(size_t)BATCH*5 + S0 + s2] = acc;
    }
  }
}

extern "C" void kernel_launch(void* const* d_in, const int* in_sizes, int n_in,
                              void* d_out, int out_size, void* d_ws, size_t ws_size,
                              hipStream_t stream){
  (void)in_sizes; (void)n_in; (void)out_size;
  const float* x     = (const float*)d_in[0];
  const float* Wproj = (const float*)d_in[1];
  const float* bproj = (const float*)d_in[2];
  const float* Wq    = (const float*)d_in[3];
  const float* Wk    = (const float*)d_in[4];
  const float* Wv    = (const float*)d_in[5];
  const float* W1    = (const float*)d_in[6];
  const float* b1    = (const float*)d_in[7];
  const float* W2    = (const float*)d_in[8];
  const float* b2    = (const float*)d_in[9];
  const float* W3    = (const float*)d_in[10];
  const float* b3    = (const float*)d_in[11];
  const float* W4    = (const float*)d_in[12];
  const float* b4    = (const float*)d_in[13];
  const float* W5    = (const float*)d_in[14];
  const float* b5    = (const float*)d_in[15];
  const float* Wmove = (const float*)d_in[16];
  const float* bmove = (const float*)d_in[17];
  const float* Wmark = (const float*)d_in[18];
  const float* bmark = (const float*)d_in[19];
  unsigned short* wpack = (unsigned short*)d_ws;
  unsigned int* swimg = (unsigned int*)(wpack + 181248);          // byte 362,496

  prep_weights<<<89, 256, 0, stream>>>(W1, W2, W3, W4, W5, wpack);
  prep_small<<<11, 256, 0, stream>>>(Wproj, bproj, Wq, Wk, Wv, Wmove, Wmark, swimg);

  // z-planes need 372,992 + 115*BATCH*4 = 60,666,112 bytes of workspace.
  const size_t Z_OFF = 372992;
  const size_t NEED  = Z_OFF + (size_t)115 * BATCH * 4;
  if (ws_size >= NEED){
    unsigned int* zg = (unsigned int*)((char*)d_ws + Z_OFF);
    attn_kernel<<<8192, 512, 0, stream>>>(x, wpack, zg);
    mlp_kernel<<<2048, 512, 0, stream>>>(zg, b1, b2, b3, b4, b5, bmove, bmark, wpack,
                                         (float*)d_out);
  } else {
    actor_main<<<4096, 768, 0, stream>>>(x,
        b1, b2, b3, b4, b5, bmove, bmark, wpack, (float*)d_out);
  }
}